// Round 2
// baseline (7813.908 us; speedup 1.0000x reference)
//
#include <hip/hip_runtime.h>
#include <hip/hip_bf16.h>

#define H 128
#define FOURH 512
#define BATCH 64
#define SEQ 2048

typedef _Float16 half8 __attribute__((ext_vector_type(8)));
typedef float f32x4 __attribute__((ext_vector_type(4)));

// ---------------- prep: transpose Wih -> [K][512], sum biases ----------------
__global__ void prep_kernel(const float* __restrict__ Wih0, const float* __restrict__ Wih1,
                            const float* __restrict__ bih0, const float* __restrict__ bhh0,
                            const float* __restrict__ bih1, const float* __restrict__ bhh1,
                            float* __restrict__ Wt0, float* __restrict__ Wt1,
                            float* __restrict__ b0, float* __restrict__ b1) {
    int id = blockIdx.x * 256 + threadIdx.x;
    const int N0 = 256 * 512;      // Wt0 elements
    const int N1 = 128 * 512;      // Wt1 elements
    if (id < N0) {
        int k = id >> 9, n = id & 511;
        Wt0[id] = Wih0[n * 256 + k];
    } else if (id < N0 + N1) {
        int i = id - N0;
        int k = i >> 9, n = i & 511;
        Wt1[i] = Wih1[n * 128 + k];
    } else if (id < N0 + N1 + 512) {
        int i = id - (N0 + N1);
        b0[i] = bih0[i] + bhh0[i];
    } else if (id < N0 + N1 + 1024) {
        int i = id - (N0 + N1 + 512);
        b1[i] = bih1[i] + bhh1[i];
    }
}

// ---------------- fp32 GEMM: G[m][n] = sum_k A[row(m)][k]*Bt[k][n] + bias[n] --
#define BM 128
#define BN 128
#define BK 32

__global__ __launch_bounds__(256) void gemm_bias_kernel(
    const float* __restrict__ A, int lda, int rowsPerBatch, int t0,
    const float* __restrict__ Bt, const float* __restrict__ bias,
    float* __restrict__ G, int K, int tcShift)
{
    __shared__ float As[BK][BM + 4];
    __shared__ float Bs[BK][BN];

    const int tid = threadIdx.x;
    const int m0 = blockIdx.y * BM;
    const int n0 = blockIdx.x * BN;
    const int tm = tid >> 4;   // 0..15
    const int tn = tid & 15;   // 0..15
    const int tcMask = (1 << tcShift) - 1;

    const float* aptr[4];
    int ar[4], aq[4];
#pragma unroll
    for (int l = 0; l < 4; ++l) {
        int fidx = tid + l * 256;
        int r = fidx >> 3, q = fidx & 7;
        ar[l] = r; aq[l] = q;
        int m = m0 + r;
        int bi = m >> tcShift;
        int tl = m & tcMask;
        aptr[l] = A + ((size_t)bi * rowsPerBatch + t0 + tl) * lda + q * 4;
    }
    int bkk[4], bq[4];
#pragma unroll
    for (int l = 0; l < 4; ++l) {
        int fidx = tid + l * 256;
        bkk[l] = fidx >> 5; bq[l] = fidx & 31;
    }

    float acc[2][2][4][4];
#pragma unroll
    for (int ri = 0; ri < 2; ++ri)
#pragma unroll
        for (int ci = 0; ci < 2; ++ci)
#pragma unroll
            for (int i = 0; i < 4; ++i)
#pragma unroll
                for (int j = 0; j < 4; ++j) acc[ri][ci][i][j] = 0.f;

    for (int k0 = 0; k0 < K; k0 += BK) {
        __syncthreads();
#pragma unroll
        for (int l = 0; l < 4; ++l) {
            float4 v = *(const float4*)(aptr[l] + k0);
            As[aq[l] * 4 + 0][ar[l]] = v.x;
            As[aq[l] * 4 + 1][ar[l]] = v.y;
            As[aq[l] * 4 + 2][ar[l]] = v.z;
            As[aq[l] * 4 + 3][ar[l]] = v.w;
        }
#pragma unroll
        for (int l = 0; l < 4; ++l) {
            float4 v = *(const float4*)(Bt + (size_t)(k0 + bkk[l]) * FOURH + n0 + bq[l] * 4);
            *(float4*)&Bs[bkk[l]][bq[l] * 4] = v;
        }
        __syncthreads();
#pragma unroll
        for (int kk = 0; kk < BK; ++kk) {
            float a[8], bb[8];
            *(float4*)&a[0] = *(const float4*)&As[kk][tm * 4];
            *(float4*)&a[4] = *(const float4*)&As[kk][64 + tm * 4];
            *(float4*)&bb[0] = *(const float4*)&Bs[kk][tn * 4];
            *(float4*)&bb[4] = *(const float4*)&Bs[kk][64 + tn * 4];
#pragma unroll
            for (int ri = 0; ri < 2; ++ri)
#pragma unroll
                for (int i = 0; i < 4; ++i)
#pragma unroll
                    for (int ci = 0; ci < 2; ++ci)
#pragma unroll
                        for (int j = 0; j < 4; ++j)
                            acc[ri][ci][i][j] = fmaf(a[ri * 4 + i], bb[ci * 4 + j], acc[ri][ci][i][j]);
        }
    }

    float4 bv0 = *(const float4*)&bias[n0 + tn * 4];
    float4 bv1 = *(const float4*)&bias[n0 + 64 + tn * 4];
#pragma unroll
    for (int ri = 0; ri < 2; ++ri)
#pragma unroll
        for (int i = 0; i < 4; ++i) {
            int m = m0 + ri * 64 + tm * 4 + i;
            float* gp = G + (size_t)m * FOURH + n0;
            float4 o0 = make_float4(acc[ri][0][i][0] + bv0.x, acc[ri][0][i][1] + bv0.y,
                                    acc[ri][0][i][2] + bv0.z, acc[ri][0][i][3] + bv0.w);
            float4 o1 = make_float4(acc[ri][1][i][0] + bv1.x, acc[ri][1][i][1] + bv1.y,
                                    acc[ri][1][i][2] + bv1.z, acc[ri][1][i][3] + bv1.w);
            *(float4*)(gp + tn * 4) = o0;
            *(float4*)(gp + 64 + tn * 4) = o1;
        }
}

// ---------------- MFMA LSTM scan ----------------
__device__ __forceinline__ float sigmoid_f(float x) {
    return __builtin_amdgcn_rcpf(1.f + __expf(-x));
}
__device__ __forceinline__ float tanh_f(float x) {
    return 1.f - 2.f * __builtin_amdgcn_rcpf(__expf(2.f * x) + 1.f);
}

// 4 blocks (16 batches each), 512 threads = 8 waves.
// Wave w owns hidden units [16w,16w+16); its 4 MFMA tiles are the i,f,g,o gate
// blocks for those units -> each lane holds i,f,g,o for (batch q*4+r, unit u)
// fully in registers after the MFMA chain. Whh stationary in 64 VGPRs/lane.
// h round-trips through double-buffered LDS as fp16; c stays fp32 in registers.
__global__ __launch_bounds__(512, 2) void lstm_scan_mfma_kernel(
    const float* __restrict__ G,      // [B][Tc][512] gate pre-activations (xw + biases)
    const float* __restrict__ Whh,    // [512][128] original layout
    float* __restrict__ Hout,
    float* __restrict__ hState, float* __restrict__ cState, // [B][128]
    int Tc, int outBatchStride, int outT0, int firstChunk)
{
    const int g  = blockIdx.x;        // batch group: batches 16g..16g+15
    const int tid = threadIdx.x;
    const int w  = tid >> 6;          // wave 0..7
    const int l  = tid & 63;
    const int li = l & 15;
    const int q  = l >> 4;            // 0..3
    const int u  = 16 * w + li;       // hidden unit this lane owns

    __shared__ _Float16 hbuf[2][16][136];   // [buf][batch][unit], +8 pad breaks 16-way bank conflict

    // ---- stationary B fragments: B[k][n]=Whh[row=tl*128+u][k], k=kf*32+q*8+j ----
    half8 Bf[4][4];
#pragma unroll
    for (int tl = 0; tl < 4; ++tl)
#pragma unroll
        for (int kf = 0; kf < 4; ++kf) {
            const float* wp = Whh + (size_t)(tl * 128 + u) * H + kf * 32 + q * 8;
            float4 v0 = *(const float4*)wp;
            float4 v1 = *(const float4*)(wp + 4);
            half8 b;
            b[0] = (_Float16)v0.x; b[1] = (_Float16)v0.y;
            b[2] = (_Float16)v0.z; b[3] = (_Float16)v0.w;
            b[4] = (_Float16)v1.x; b[5] = (_Float16)v1.y;
            b[6] = (_Float16)v1.z; b[7] = (_Float16)v1.w;
            Bf[tl][kf] = b;
        }

    // ---- state init ----
    float c[4], hreg[4];
#pragma unroll
    for (int r = 0; r < 4; ++r) {
        int bg = 16 * g + q * 4 + r;
        float hv = 0.f; c[r] = 0.f;
        if (!firstChunk) { hv = hState[bg * H + u]; c[r] = cState[bg * H + u]; }
        hreg[r] = hv;
        hbuf[0][q * 4 + r][u] = (_Float16)hv;
    }

    // ---- G addressing: uniform base advancing 512 floats/step + static voffsets ----
    const float* gbase = G + (size_t)(16 * g) * Tc * FOURH;
    int goff[16];
#pragma unroll
    for (int tl = 0; tl < 4; ++tl)
#pragma unroll
        for (int r = 0; r < 4; ++r)
            goff[tl * 4 + r] = (q * 4 + r) * Tc * FOURH + tl * H + u;

    float* hout = Hout + ((size_t)(16 * g) * outBatchStride + outT0) * H;
    int hoff[4];
#pragma unroll
    for (int r = 0; r < 4; ++r) hoff[r] = (q * 4 + r) * outBatchStride * H + u;

    float Gc[16], Gn[16];
#pragma unroll
    for (int i = 0; i < 16; ++i) Gc[i] = gbase[goff[i]];

    __syncthreads();

    for (int s = 0; s < Tc; ++s) {
        // prefetch next step's G (landed by the time we rotate at loop end)
        int sn = (s + 1 < Tc) ? s + 1 : s;
        const float* gp = gbase + (size_t)sn * FOURH;
#pragma unroll
        for (int i = 0; i < 16; ++i) Gn[i] = gp[goff[i]];

        // A fragments: h[batch=li][k] fp16 from LDS
        const int pb = s & 1;
        half8 A[4];
#pragma unroll
        for (int kf = 0; kf < 4; ++kf)
            A[kf] = *(const half8*)&hbuf[pb][li][kf * 32 + q * 8];

        // gates = G + h @ Whh_perm : 16 MFMAs, 4 independent chains
        f32x4 acc[4];
#pragma unroll
        for (int tl = 0; tl < 4; ++tl) {
            acc[tl][0] = Gc[tl * 4 + 0]; acc[tl][1] = Gc[tl * 4 + 1];
            acc[tl][2] = Gc[tl * 4 + 2]; acc[tl][3] = Gc[tl * 4 + 3];
        }
#pragma unroll
        for (int kf = 0; kf < 4; ++kf)
#pragma unroll
            for (int tl = 0; tl < 4; ++tl)
                acc[tl] = __builtin_amdgcn_mfma_f32_16x16x32_f16(A[kf], Bf[tl][kf], acc[tl], 0, 0, 0);

        // activations + state update, all in registers
#pragma unroll
        for (int r = 0; r < 4; ++r) {
            float ig = sigmoid_f(acc[0][r]);
            float fg = sigmoid_f(acc[1][r]);
            float gg = tanh_f(acc[2][r]);
            float og = sigmoid_f(acc[3][r]);
            c[r] = fmaf(fg, c[r], ig * gg);
            float h = og * tanh_f(c[r]);
            hreg[r] = h;
            hbuf[pb ^ 1][q * 4 + r][u] = (_Float16)h;   // for next step's A-frags
            hout[hoff[r]] = h;                           // fp32 hidden output
        }
        hout += H;
#pragma unroll
        for (int i = 0; i < 16; ++i) Gc[i] = Gn[i];
        __syncthreads();
    }

#pragma unroll
    for (int r = 0; r < 4; ++r) {
        int bg = 16 * g + q * 4 + r;
        hState[bg * H + u] = hreg[r];
        cState[bg * H + u] = c[r];
    }
}

// ---------------- launch ----------------
extern "C" void kernel_launch(void* const* d_in, const int* in_sizes, int n_in,
                              void* d_out, int out_size, void* d_ws, size_t ws_size,
                              hipStream_t stream) {
    const float* x    = (const float*)d_in[0];
    const float* Wih0 = (const float*)d_in[1];
    const float* Whh0 = (const float*)d_in[2];
    const float* bih0 = (const float*)d_in[3];
    const float* bhh0 = (const float*)d_in[4];
    const float* Wih1 = (const float*)d_in[5];
    const float* Whh1 = (const float*)d_in[6];
    const float* bih1 = (const float*)d_in[7];
    const float* bhh1 = (const float*)d_in[8];
    float* out = (float*)d_out;

    char* ws = (char*)d_ws;
    size_t off = 0;
    auto carve = [&](size_t bytes) -> char* {
        char* p = ws + off;
        off += (bytes + 255) & ~(size_t)255;
        return p;
    };

    float* Wt0 = (float*)carve(256 * 512 * 4);
    float* Wt1 = (float*)carve(128 * 512 * 4);
    float* b0  = (float*)carve(512 * 4);
    float* b1  = (float*)carve(512 * 4);
    float* h0s = (float*)carve(BATCH * H * 4);
    float* c0s = (float*)carve(BATCH * H * 4);
    float* h1s = (float*)carve(BATCH * H * 4);
    float* c1s = (float*)carve(BATCH * H * 4);

    int Tc = 2048;
    for (;;) {
        size_t need = off + (size_t)BATCH * Tc * FOURH * 4 + (size_t)BATCH * Tc * H * 4 + 4096;
        if (need <= ws_size || Tc == 128) break;
        Tc >>= 1;
    }
    float* gbuf  = (float*)carve((size_t)BATCH * Tc * FOURH * 4);
    float* h1buf = (float*)carve((size_t)BATCH * Tc * H * 4);
    int tcShift = 31 - __builtin_clz((unsigned)Tc);

    prep_kernel<<<772, 256, 0, stream>>>(Wih0, Wih1, bih0, bhh0, bih1, bhh1, Wt0, Wt1, b0, b1);

    const int nChunks = SEQ / Tc;
    dim3 ggrid(FOURH / BN, (BATCH * Tc) / BM);
    for (int c = 0; c < nChunks; ++c) {
        int t0 = c * Tc;
        gemm_bias_kernel<<<ggrid, 256, 0, stream>>>(x, 256, SEQ, t0, Wt0, b0, gbuf, 256, tcShift);
        lstm_scan_mfma_kernel<<<BATCH / 16, 512, 0, stream>>>(gbuf, Whh0, h1buf, h0s, c0s,
                                                              Tc, Tc, 0, c == 0 ? 1 : 0);
        gemm_bias_kernel<<<ggrid, 256, 0, stream>>>(h1buf, 128, Tc, 0, Wt1, b1, gbuf, 128, tcShift);
        lstm_scan_mfma_kernel<<<BATCH / 16, 512, 0, stream>>>(gbuf, Whh1, out, h1s, c1s,
                                                              Tc, SEQ, t0, c == 0 ? 1 : 0);
    }
}

// Round 3
// 3953.112 us; speedup vs baseline: 1.9766x; 1.9766x over previous
//
#include <hip/hip_runtime.h>
#include <hip/hip_bf16.h>

#define H 128
#define FOURH 512
#define BATCH 64
#define SEQ 2048

typedef _Float16 half8 __attribute__((ext_vector_type(8)));
typedef float f32x4 __attribute__((ext_vector_type(4)));

// ---------------- prep: transpose Wih -> [K][512], sum biases ----------------
__global__ void prep_kernel(const float* __restrict__ Wih0, const float* __restrict__ Wih1,
                            const float* __restrict__ bih0, const float* __restrict__ bhh0,
                            const float* __restrict__ bih1, const float* __restrict__ bhh1,
                            float* __restrict__ Wt0, float* __restrict__ Wt1,
                            float* __restrict__ b0, float* __restrict__ b1) {
    int id = blockIdx.x * 256 + threadIdx.x;
    const int N0 = 256 * 512;
    const int N1 = 128 * 512;
    if (id < N0) {
        int k = id >> 9, n = id & 511;
        Wt0[id] = Wih0[n * 256 + k];
    } else if (id < N0 + N1) {
        int i = id - N0;
        int k = i >> 9, n = i & 511;
        Wt1[i] = Wih1[n * 128 + k];
    } else if (id < N0 + N1 + 512) {
        int i = id - (N0 + N1);
        b0[i] = bih0[i] + bhh0[i];
    } else if (id < N0 + N1 + 1024) {
        int i = id - (N0 + N1 + 512);
        b1[i] = bih1[i] + bhh1[i];
    }
}

// ---------------- fp32 GEMM (unchanged from round 1/2) ----------------
#define BM 128
#define BN 128
#define BK 32

__global__ __launch_bounds__(256) void gemm_bias_kernel(
    const float* __restrict__ A, int lda, int rowsPerBatch, int t0,
    const float* __restrict__ Bt, const float* __restrict__ bias,
    float* __restrict__ G, int K, int tcShift)
{
    __shared__ float As[BK][BM + 4];
    __shared__ float Bs[BK][BN];

    const int tid = threadIdx.x;
    const int m0 = blockIdx.y * BM;
    const int n0 = blockIdx.x * BN;
    const int tm = tid >> 4;
    const int tn = tid & 15;
    const int tcMask = (1 << tcShift) - 1;

    const float* aptr[4];
    int ar[4], aq[4];
#pragma unroll
    for (int l = 0; l < 4; ++l) {
        int fidx = tid + l * 256;
        int r = fidx >> 3, q = fidx & 7;
        ar[l] = r; aq[l] = q;
        int m = m0 + r;
        int bi = m >> tcShift;
        int tl = m & tcMask;
        aptr[l] = A + ((size_t)bi * rowsPerBatch + t0 + tl) * lda + q * 4;
    }
    int bkk[4], bq[4];
#pragma unroll
    for (int l = 0; l < 4; ++l) {
        int fidx = tid + l * 256;
        bkk[l] = fidx >> 5; bq[l] = fidx & 31;
    }

    float acc[2][2][4][4];
#pragma unroll
    for (int ri = 0; ri < 2; ++ri)
#pragma unroll
        for (int ci = 0; ci < 2; ++ci)
#pragma unroll
            for (int i = 0; i < 4; ++i)
#pragma unroll
                for (int j = 0; j < 4; ++j) acc[ri][ci][i][j] = 0.f;

    for (int k0 = 0; k0 < K; k0 += BK) {
        __syncthreads();
#pragma unroll
        for (int l = 0; l < 4; ++l) {
            float4 v = *(const float4*)(aptr[l] + k0);
            As[aq[l] * 4 + 0][ar[l]] = v.x;
            As[aq[l] * 4 + 1][ar[l]] = v.y;
            As[aq[l] * 4 + 2][ar[l]] = v.z;
            As[aq[l] * 4 + 3][ar[l]] = v.w;
        }
#pragma unroll
        for (int l = 0; l < 4; ++l) {
            float4 v = *(const float4*)(Bt + (size_t)(k0 + bkk[l]) * FOURH + n0 + bq[l] * 4);
            *(float4*)&Bs[bkk[l]][bq[l] * 4] = v;
        }
        __syncthreads();
#pragma unroll
        for (int kk = 0; kk < BK; ++kk) {
            float a[8], bb[8];
            *(float4*)&a[0] = *(const float4*)&As[kk][tm * 4];
            *(float4*)&a[4] = *(const float4*)&As[kk][64 + tm * 4];
            *(float4*)&bb[0] = *(const float4*)&Bs[kk][tn * 4];
            *(float4*)&bb[4] = *(const float4*)&Bs[kk][64 + tn * 4];
#pragma unroll
            for (int ri = 0; ri < 2; ++ri)
#pragma unroll
                for (int i = 0; i < 4; ++i)
#pragma unroll
                    for (int ci = 0; ci < 2; ++ci)
#pragma unroll
                        for (int j = 0; j < 4; ++j)
                            acc[ri][ci][i][j] = fmaf(a[ri * 4 + i], bb[ci * 4 + j], acc[ri][ci][i][j]);
        }
    }

    float4 bv0 = *(const float4*)&bias[n0 + tn * 4];
    float4 bv1 = *(const float4*)&bias[n0 + 64 + tn * 4];
#pragma unroll
    for (int ri = 0; ri < 2; ++ri)
#pragma unroll
        for (int i = 0; i < 4; ++i) {
            int m = m0 + ri * 64 + tm * 4 + i;
            float* gp = G + (size_t)m * FOURH + n0;
            float4 o0 = make_float4(acc[ri][0][i][0] + bv0.x, acc[ri][0][i][1] + bv0.y,
                                    acc[ri][0][i][2] + bv0.z, acc[ri][0][i][3] + bv0.w);
            float4 o1 = make_float4(acc[ri][1][i][0] + bv1.x, acc[ri][1][i][1] + bv1.y,
                                    acc[ri][1][i][2] + bv1.z, acc[ri][1][i][3] + bv1.w);
            *(float4*)(gp + tn * 4) = o0;
            *(float4*)(gp + 64 + tn * 4) = o1;
        }
}

// ---------------- MFMA LSTM scan, 8 blocks x 8 batches ----------------
__device__ __forceinline__ float sigmoid_f(float x) {
    return __builtin_amdgcn_rcpf(1.f + __expf(-x));
}
__device__ __forceinline__ float tanh_f(float x) {
    return 1.f - 2.f * __builtin_amdgcn_rcpf(__expf(2.f * x) + 1.f);
}

// 8 blocks (8 batches each), 512 threads = 8 waves.
// Real batches live in C-rows q*4+{0,1} (batch = q*2+r, r<2) -> activation
// work halves vs 16-batch mapping; rows with (row&3)>=2 are garbage (read
// duplicated valid h, never stored). Whh stationary in 64 VGPRs/lane.
// h: fp16 double-buffered LDS. hout: staged in LDS, flushed every 8 steps
// (amortizes the vmcnt(0) store drain at the barrier 8x).
__global__ __launch_bounds__(512, 1) void lstm_scan_mfma_kernel(
    const float* __restrict__ G,      // [B][Tc][512] gate pre-activations
    const float* __restrict__ Whh,    // [512][128]
    float* __restrict__ Hout,
    float* __restrict__ hState, float* __restrict__ cState, // [B][128]
    int Tc, int outBatchStride, int outT0, int firstChunk)
{
    const int g   = blockIdx.x;       // batches 8g..8g+7
    const int tid = threadIdx.x;
    const int w   = tid >> 6;         // wave 0..7
    const int l   = tid & 63;
    const int li  = l & 15;
    const int q   = l >> 4;           // 0..3
    const int u   = 16 * w + li;      // hidden unit this lane owns (C col)

    __shared__ _Float16 hbuf[2][8][136];   // [buf][batch][unit] (16B-aligned rows)
    __shared__ float houtb[8][8][132];     // [step&7][batch][unit] staging

    // ---- stationary B fragments: B[k][n]=Whh[row=tl*128+u][k], k=kf*32+q*8+j ----
    half8 Bf[4][4];
#pragma unroll
    for (int tl = 0; tl < 4; ++tl)
#pragma unroll
        for (int kf = 0; kf < 4; ++kf) {
            const float* wp = Whh + (size_t)(tl * 128 + u) * H + kf * 32 + q * 8;
            float4 v0 = *(const float4*)wp;
            float4 v1 = *(const float4*)(wp + 4);
            half8 b;
            b[0] = (_Float16)v0.x; b[1] = (_Float16)v0.y;
            b[2] = (_Float16)v0.z; b[3] = (_Float16)v0.w;
            b[4] = (_Float16)v1.x; b[5] = (_Float16)v1.y;
            b[6] = (_Float16)v1.z; b[7] = (_Float16)v1.w;
            Bf[tl][kf] = b;
        }

    // this lane's real batches (rows q*4+0, q*4+1)
    const int b0 = q * 2;                          // local batch for r=0 (r=1 -> b0+1)
    // A-row source batch: row li -> batch (li>>2)*2 + (li&1)  (garbage rows dup a valid batch)
    const int ab = ((li >> 2) * 2) + (li & 1);

    // ---- state init ----
    float c0 = 0.f, c1 = 0.f, h0 = 0.f, h1 = 0.f;
    if (!firstChunk) {
        h0 = hState[(8 * g + b0) * H + u];     c0 = cState[(8 * g + b0) * H + u];
        h1 = hState[(8 * g + b0 + 1) * H + u]; c1 = cState[(8 * g + b0 + 1) * H + u];
    }
    hbuf[0][b0][u]     = (_Float16)h0;
    hbuf[0][b0 + 1][u] = (_Float16)h1;

    // ---- G addressing: uniform base (stepped by 512 floats) + 2 lane voffsets + tl*128 imm ----
    const float* gb = G + (size_t)(8 * g) * Tc * FOURH;
    const int voff0 = b0 * Tc * FOURH + u;
    const int voff1 = (b0 + 1) * Tc * FOURH + u;

    float Gc[8], Gn[8];
#pragma unroll
    for (int tl = 0; tl < 4; ++tl) {
        Gc[tl * 2 + 0] = gb[voff0 + tl * H];
        Gc[tl * 2 + 1] = gb[voff1 + tl * H];
    }
    const float* gnext = gb + FOURH;

    float* houtBase = Hout + ((size_t)(8 * g) * outBatchStride + outT0) * H;

    __syncthreads();

#define LSTM_STEP(S, PB)                                                          \
    {                                                                             \
        /* prefetch next step's G (in flight for the whole step) */               \
        _Pragma("unroll")                                                         \
        for (int tl = 0; tl < 4; ++tl) {                                          \
            Gn[tl * 2 + 0] = gnext[voff0 + tl * H];                               \
            Gn[tl * 2 + 1] = gnext[voff1 + tl * H];                               \
        }                                                                         \
        gnext += FOURH;                                                           \
        half8 Afr[4];                                                             \
        _Pragma("unroll")                                                         \
        for (int kf = 0; kf < 4; ++kf)                                            \
            Afr[kf] = *(const half8*)&hbuf[PB][ab][kf * 32 + q * 8];              \
        f32x4 acc[4];                                                             \
        _Pragma("unroll")                                                         \
        for (int tl = 0; tl < 4; ++tl) {                                          \
            acc[tl][0] = Gc[tl * 2 + 0]; acc[tl][1] = Gc[tl * 2 + 1];             \
            acc[tl][2] = 0.f;            acc[tl][3] = 0.f;                        \
        }                                                                         \
        _Pragma("unroll")                                                         \
        for (int kf = 0; kf < 4; ++kf)                                            \
            _Pragma("unroll")                                                     \
            for (int tl = 0; tl < 4; ++tl)                                        \
                acc[tl] = __builtin_amdgcn_mfma_f32_16x16x32_f16(Afr[kf], Bf[tl][kf], acc[tl], 0, 0, 0); \
        {                                                                         \
            float ig = sigmoid_f(acc[0][0]);                                      \
            float fg = sigmoid_f(acc[1][0]);                                      \
            float gg = tanh_f(acc[2][0]);                                         \
            float og = sigmoid_f(acc[3][0]);                                      \
            c0 = fmaf(fg, c0, ig * gg);                                           \
            h0 = og * tanh_f(c0);                                                 \
            float ig1 = sigmoid_f(acc[0][1]);                                     \
            float fg1 = sigmoid_f(acc[1][1]);                                     \
            float gg1 = tanh_f(acc[2][1]);                                        \
            float og1 = sigmoid_f(acc[3][1]);                                     \
            c1 = fmaf(fg1, c1, ig1 * gg1);                                        \
            h1 = og1 * tanh_f(c1);                                                \
        }                                                                         \
        hbuf[PB ^ 1][b0][u]     = (_Float16)h0;                                   \
        hbuf[PB ^ 1][b0 + 1][u] = (_Float16)h1;                                   \
        houtb[(S) & 7][b0][u]     = h0;                                           \
        houtb[(S) & 7][b0 + 1][u] = h1;                                           \
        _Pragma("unroll")                                                         \
        for (int i = 0; i < 8; ++i) Gc[i] = Gn[i];                                \
        __syncthreads();                                                          \
    }

    for (int s2 = 0; s2 < Tc; s2 += 2) {
        LSTM_STEP(s2, 0)
        LSTM_STEP(s2 + 1, 1)
        if ((s2 & 7) == 6) {
            // flush steps s2-6 .. s2+1 (8 steps) with coalesced stores
            int sbase = s2 - 6;
#pragma unroll
            for (int k = 0; k < 4; ++k) {
                int idx = k * 512 + tid;          // 0..2047 float4s
                int u4 = idx & 31;                // unit/4
                int si = (idx >> 5) & 7;          // step within group
                int bi = idx >> 8;                // batch 0..7
                float4 v = *(const float4*)&houtb[si][bi][u4 * 4];
                float* dst = houtBase + (size_t)bi * outBatchStride * H
                           + (size_t)(sbase + si) * H + u4 * 4;
                *(float4*)dst = v;
            }
            __syncthreads();
        }
    }
#undef LSTM_STEP

    hState[(8 * g + b0) * H + u]     = h0;  cState[(8 * g + b0) * H + u]     = c0;
    hState[(8 * g + b0 + 1) * H + u] = h1;  cState[(8 * g + b0 + 1) * H + u] = c1;
}

// ---------------- launch ----------------
extern "C" void kernel_launch(void* const* d_in, const int* in_sizes, int n_in,
                              void* d_out, int out_size, void* d_ws, size_t ws_size,
                              hipStream_t stream) {
    const float* x    = (const float*)d_in[0];
    const float* Wih0 = (const float*)d_in[1];
    const float* Whh0 = (const float*)d_in[2];
    const float* bih0 = (const float*)d_in[3];
    const float* bhh0 = (const float*)d_in[4];
    const float* Wih1 = (const float*)d_in[5];
    const float* Whh1 = (const float*)d_in[6];
    const float* bih1 = (const float*)d_in[7];
    const float* bhh1 = (const float*)d_in[8];
    float* out = (float*)d_out;

    char* ws = (char*)d_ws;
    size_t off = 0;
    auto carve = [&](size_t bytes) -> char* {
        char* p = ws + off;
        off += (bytes + 255) & ~(size_t)255;
        return p;
    };

    float* Wt0 = (float*)carve(256 * 512 * 4);
    float* Wt1 = (float*)carve(128 * 512 * 4);
    float* b0  = (float*)carve(512 * 4);
    float* b1  = (float*)carve(512 * 4);
    float* h0s = (float*)carve(BATCH * H * 4);
    float* c0s = (float*)carve(BATCH * H * 4);
    float* h1s = (float*)carve(BATCH * H * 4);
    float* c1s = (float*)carve(BATCH * H * 4);

    int Tc = 2048;
    for (;;) {
        size_t need = off + (size_t)BATCH * Tc * FOURH * 4 + (size_t)BATCH * Tc * H * 4 + 4096;
        if (need <= ws_size || Tc == 128) break;
        Tc >>= 1;
    }
    float* gbuf  = (float*)carve((size_t)BATCH * Tc * FOURH * 4);
    float* h1buf = (float*)carve((size_t)BATCH * Tc * H * 4);
    int tcShift = 31 - __builtin_clz((unsigned)Tc);

    prep_kernel<<<772, 256, 0, stream>>>(Wih0, Wih1, bih0, bhh0, bih1, bhh1, Wt0, Wt1, b0, b1);

    const int nChunks = SEQ / Tc;
    dim3 ggrid(FOURH / BN, (BATCH * Tc) / BM);
    for (int c = 0; c < nChunks; ++c) {
        int t0 = c * Tc;
        gemm_bias_kernel<<<ggrid, 256, 0, stream>>>(x, 256, SEQ, t0, Wt0, b0, gbuf, 256, tcShift);
        lstm_scan_mfma_kernel<<<BATCH / 8, 512, 0, stream>>>(gbuf, Whh0, h1buf, h0s, c0s,
                                                             Tc, Tc, 0, c == 0 ? 1 : 0);
        gemm_bias_kernel<<<ggrid, 256, 0, stream>>>(h1buf, 128, Tc, 0, Wt1, b1, gbuf, 128, tcShift);
        lstm_scan_mfma_kernel<<<BATCH / 8, 512, 0, stream>>>(gbuf, Whh1, out, h1s, c1s,
                                                             Tc, SEQ, t0, c == 0 ? 1 : 0);
    }
}

// Round 4
// 2783.513 us; speedup vs baseline: 2.8072x; 1.4202x over previous
//
#include <hip/hip_runtime.h>
#include <hip/hip_bf16.h>

#define H 128
#define FOURH 512
#define BATCH 64
#define SEQ 2048
#define TC SEQ

typedef _Float16 half8 __attribute__((ext_vector_type(8)));
typedef float f32x4 __attribute__((ext_vector_type(4)));

// ---------------- prep: transpose Wih0 -> [K][512], sum biases, zero flags ----
__global__ void prep_kernel(const float* __restrict__ Wih0,
                            const float* __restrict__ bih0, const float* __restrict__ bhh0,
                            const float* __restrict__ bih1, const float* __restrict__ bhh1,
                            float* __restrict__ Wt0,
                            float* __restrict__ b0, float* __restrict__ b1,
                            int* __restrict__ flags) {
    int id = blockIdx.x * 256 + threadIdx.x;
    const int N0 = 256 * 512;
    if (id < N0) {
        int k = id >> 9, n = id & 511;
        Wt0[id] = Wih0[n * 256 + k];
    } else if (id < N0 + 512) {
        int i = id - N0;
        b0[i] = bih0[i] + bhh0[i];
    } else if (id < N0 + 1024) {
        int i = id - (N0 + 512);
        b1[i] = bih1[i] + bhh1[i];
    } else if (id < N0 + 1024 + 8) {
        flags[id - (N0 + 1024)] = 0;
    }
}

// ---------------- fp32 GEMM: G[m][n] = sum_k A[row(m)][k]*Bt[k][n] + bias[n] --
#define BM 128
#define BN 128
#define BK 32

__global__ __launch_bounds__(256) void gemm_bias_kernel(
    const float* __restrict__ A, int lda, int rowsPerBatch, int t0,
    const float* __restrict__ Bt, const float* __restrict__ bias,
    float* __restrict__ G, int K, int tcShift)
{
    __shared__ float As[BK][BM + 4];
    __shared__ float Bs[BK][BN];

    const int tid = threadIdx.x;
    const int m0 = blockIdx.y * BM;
    const int n0 = blockIdx.x * BN;
    const int tm = tid >> 4;
    const int tn = tid & 15;
    const int tcMask = (1 << tcShift) - 1;

    const float* aptr[4];
    int ar[4], aq[4];
#pragma unroll
    for (int l = 0; l < 4; ++l) {
        int fidx = tid + l * 256;
        int r = fidx >> 3, q = fidx & 7;
        ar[l] = r; aq[l] = q;
        int m = m0 + r;
        int bi = m >> tcShift;
        int tl = m & tcMask;
        aptr[l] = A + ((size_t)bi * rowsPerBatch + t0 + tl) * lda + q * 4;
    }
    int bkk[4], bq[4];
#pragma unroll
    for (int l = 0; l < 4; ++l) {
        int fidx = tid + l * 256;
        bkk[l] = fidx >> 5; bq[l] = fidx & 31;
    }

    float acc[2][2][4][4];
#pragma unroll
    for (int ri = 0; ri < 2; ++ri)
#pragma unroll
        for (int ci = 0; ci < 2; ++ci)
#pragma unroll
            for (int i = 0; i < 4; ++i)
#pragma unroll
                for (int j = 0; j < 4; ++j) acc[ri][ci][i][j] = 0.f;

    for (int k0 = 0; k0 < K; k0 += BK) {
        __syncthreads();
#pragma unroll
        for (int l = 0; l < 4; ++l) {
            float4 v = *(const float4*)(aptr[l] + k0);
            As[aq[l] * 4 + 0][ar[l]] = v.x;
            As[aq[l] * 4 + 1][ar[l]] = v.y;
            As[aq[l] * 4 + 2][ar[l]] = v.z;
            As[aq[l] * 4 + 3][ar[l]] = v.w;
        }
#pragma unroll
        for (int l = 0; l < 4; ++l) {
            float4 v = *(const float4*)(Bt + (size_t)(k0 + bkk[l]) * FOURH + n0 + bq[l] * 4);
            *(float4*)&Bs[bkk[l]][bq[l] * 4] = v;
        }
        __syncthreads();
#pragma unroll
        for (int kk = 0; kk < BK; ++kk) {
            float a[8], bb[8];
            *(float4*)&a[0] = *(const float4*)&As[kk][tm * 4];
            *(float4*)&a[4] = *(const float4*)&As[kk][64 + tm * 4];
            *(float4*)&bb[0] = *(const float4*)&Bs[kk][tn * 4];
            *(float4*)&bb[4] = *(const float4*)&Bs[kk][64 + tn * 4];
#pragma unroll
            for (int ri = 0; ri < 2; ++ri)
#pragma unroll
                for (int i = 0; i < 4; ++i)
#pragma unroll
                    for (int ci = 0; ci < 2; ++ci)
#pragma unroll
                        for (int j = 0; j < 4; ++j)
                            acc[ri][ci][i][j] = fmaf(a[ri * 4 + i], bb[ci * 4 + j], acc[ri][ci][i][j]);
        }
    }

    float4 bv0 = *(const float4*)&bias[n0 + tn * 4];
    float4 bv1 = *(const float4*)&bias[n0 + 64 + tn * 4];
#pragma unroll
    for (int ri = 0; ri < 2; ++ri)
#pragma unroll
        for (int i = 0; i < 4; ++i) {
            int m = m0 + ri * 64 + tm * 4 + i;
            float* gp = G + (size_t)m * FOURH + n0;
            float4 o0 = make_float4(acc[ri][0][i][0] + bv0.x, acc[ri][0][i][1] + bv0.y,
                                    acc[ri][0][i][2] + bv0.z, acc[ri][0][i][3] + bv0.w);
            float4 o1 = make_float4(acc[ri][1][i][0] + bv1.x, acc[ri][1][i][1] + bv1.y,
                                    acc[ri][1][i][2] + bv1.z, acc[ri][1][i][3] + bv1.w);
            *(float4*)(gp + tn * 4) = o0;
            *(float4*)(gp + 64 + tn * 4) = o1;
        }
}

// ---------------- fused 2-layer MFMA LSTM scan (producer/consumer) ----------------
__device__ __forceinline__ float sigmoid_f(float x) {
    return __builtin_amdgcn_rcpf(1.f + __expf(-x));
}
__device__ __forceinline__ float tanh_f(float x) {
    return 1.f - 2.f * __builtin_amdgcn_rcpf(__expf(2.f * x) + 1.f);
}

// 16 blocks x 512 threads. Blocks 0-7: layer 0 over batches 8g..8g+7 (reads
// precomputed G=xW+b, publishes h1 to ws as fp16 + release flag every 8 steps).
// Blocks 8-15: layer 1, same batch split; per step gates = b1 + h1_t@Wih1^T +
// h2_{t-1}@Whh1^T as one K=256 MFMA chain (input GEMM fused). Consumer lags
// producer >=16 steps via agent-scope acquire spins. 16 blocks are always
// co-resident on 256 CUs; stream order guarantees gemm0 completed.
__global__ __launch_bounds__(512, 2) void lstm_fused_kernel(
    const float* __restrict__ G,      // [64][T][512] layer-0 gate pre-activations
    const float* __restrict__ Whh0,   // [512][128]
    const float* __restrict__ Wih1,   // [512][128]
    const float* __restrict__ Whh1,   // [512][128]
    const float* __restrict__ b1,     // [512] summed layer-1 biases
    _Float16* __restrict__ h1p,       // [T][64][128] fp16 layer-0 hidden (pipe buffer)
    float* __restrict__ out,          // [64][T][128] fp32 layer-1 hidden
    int* __restrict__ flags)          // [8] progress counters (prep zeroed)
{
    const int tid = threadIdx.x;
    const int w  = tid >> 6;
    const int l  = tid & 63;
    const int li = l & 15;
    const int q  = l >> 4;
    const int u  = 16 * w + li;                 // owned hidden unit (C col)
    const int b0 = q * 2;                       // local batch for C-row r=0
    const int ab = ((li >> 2) * 2) + (li & 1);  // A-row -> local batch (dup map)

    __shared__ _Float16 hbuf[2][8][136];        // recurrent h, fp16, dbuf
    __shared__ float houtb[8][8][132];          // consumer output staging

    if (blockIdx.x < 8) {
        // ================= producer: layer 0 =================
        const int g = blockIdx.x;

        half8 Bf[4][4];
#pragma unroll
        for (int tl = 0; tl < 4; ++tl)
#pragma unroll
            for (int kf = 0; kf < 4; ++kf) {
                const float* wp = Whh0 + (size_t)(tl * 128 + u) * H + kf * 32 + q * 8;
                float4 v0 = *(const float4*)wp;
                float4 v1 = *(const float4*)(wp + 4);
                half8 b;
                b[0] = (_Float16)v0.x; b[1] = (_Float16)v0.y;
                b[2] = (_Float16)v0.z; b[3] = (_Float16)v0.w;
                b[4] = (_Float16)v1.x; b[5] = (_Float16)v1.y;
                b[6] = (_Float16)v1.z; b[7] = (_Float16)v1.w;
                Bf[tl][kf] = b;
            }

        float c0 = 0.f, c1 = 0.f, h0 = 0.f, h1v = 0.f;
        hbuf[0][b0][u]     = (_Float16)0.f;
        hbuf[0][b0 + 1][u] = (_Float16)0.f;

        const float* gb = G + (size_t)(8 * g) * TC * FOURH;
        const int voff0 = b0 * TC * FOURH + u;
        const int voff1 = (b0 + 1) * TC * FOURH + u;

        float Gc[8], Gn[8];
#pragma unroll
        for (int tl = 0; tl < 4; ++tl) {
            Gc[tl * 2 + 0] = gb[voff0 + tl * H];
            Gc[tl * 2 + 1] = gb[voff1 + tl * H];
        }
        const float* gnext = gb + FOURH;

        _Float16* php = h1p + (size_t)(8 * g + b0) * H + u;   // +step*8192
        __syncthreads();

#define P_STEP(S, PB)                                                             \
    {                                                                             \
        _Pragma("unroll")                                                         \
        for (int tl = 0; tl < 4; ++tl) {                                          \
            Gn[tl * 2 + 0] = gnext[voff0 + tl * H];                               \
            Gn[tl * 2 + 1] = gnext[voff1 + tl * H];                               \
        }                                                                         \
        gnext += FOURH;                                                           \
        half8 Afr[4];                                                             \
        _Pragma("unroll")                                                         \
        for (int kf = 0; kf < 4; ++kf)                                            \
            Afr[kf] = *(const half8*)&hbuf[PB][ab][kf * 32 + q * 8];              \
        f32x4 acc[4];                                                             \
        _Pragma("unroll")                                                         \
        for (int tl = 0; tl < 4; ++tl) {                                          \
            acc[tl][0] = Gc[tl * 2 + 0]; acc[tl][1] = Gc[tl * 2 + 1];             \
            acc[tl][2] = 0.f;            acc[tl][3] = 0.f;                        \
        }                                                                         \
        _Pragma("unroll")                                                         \
        for (int kf = 0; kf < 4; ++kf)                                            \
            _Pragma("unroll")                                                     \
            for (int tl = 0; tl < 4; ++tl)                                        \
                acc[tl] = __builtin_amdgcn_mfma_f32_16x16x32_f16(Afr[kf], Bf[tl][kf], acc[tl], 0, 0, 0); \
        {                                                                         \
            float ig = sigmoid_f(acc[0][0]);                                      \
            float fg = sigmoid_f(acc[1][0]);                                      \
            float gg = tanh_f(acc[2][0]);                                         \
            float og = sigmoid_f(acc[3][0]);                                      \
            c0 = fmaf(fg, c0, ig * gg);                                           \
            h0 = og * tanh_f(c0);                                                 \
            float ig1 = sigmoid_f(acc[0][1]);                                     \
            float fg1 = sigmoid_f(acc[1][1]);                                     \
            float gg1 = tanh_f(acc[2][1]);                                        \
            float og1 = sigmoid_f(acc[3][1]);                                     \
            c1 = fmaf(fg1, c1, ig1 * gg1);                                        \
            h1v = og1 * tanh_f(c1);                                               \
        }                                                                         \
        hbuf[PB ^ 1][b0][u]     = (_Float16)h0;                                   \
        hbuf[PB ^ 1][b0 + 1][u] = (_Float16)h1v;                                  \
        php[0]   = (_Float16)h0;                                                  \
        php[128] = (_Float16)h1v;                                                 \
        php += BATCH * H;                                                         \
        _Pragma("unroll")                                                         \
        for (int i = 0; i < 8; ++i) Gc[i] = Gn[i];                                \
        __syncthreads();                                                          \
    }

        for (int s2 = 0; s2 < TC; s2 += 2) {
            P_STEP(s2, 0)
            P_STEP(s2 + 1, 1)
            if ((s2 & 7) == 6) {
                __threadfence();            // drain + make h1p stores device-visible
                __syncthreads();            // all waves fenced before flag
                if (tid == 0)
                    __hip_atomic_store(&flags[g], s2 + 2, __ATOMIC_RELEASE,
                                       __HIP_MEMORY_SCOPE_AGENT);
            }
        }
#undef P_STEP
    } else {
        // ================= consumer: layer 1 =================
        const int g = blockIdx.x - 8;

        // Bf[tl][kf]: kf<4 from Wih1 (applies to h1_t), kf>=4 from Whh1 (h2_{t-1})
        half8 Bf[4][8];
#pragma unroll
        for (int tl = 0; tl < 4; ++tl)
#pragma unroll
            for (int kf = 0; kf < 8; ++kf) {
                const float* base = (kf < 4) ? Wih1 : Whh1;
                int kk = (kf & 3) * 32 + q * 8;
                const float* wp = base + (size_t)(tl * 128 + u) * H + kk;
                float4 v0 = *(const float4*)wp;
                float4 v1 = *(const float4*)(wp + 4);
                half8 b;
                b[0] = (_Float16)v0.x; b[1] = (_Float16)v0.y;
                b[2] = (_Float16)v0.z; b[3] = (_Float16)v0.w;
                b[4] = (_Float16)v1.x; b[5] = (_Float16)v1.y;
                b[6] = (_Float16)v1.z; b[7] = (_Float16)v1.w;
                Bf[tl][kf] = b;
            }

        float bv[4];
#pragma unroll
        for (int tl = 0; tl < 4; ++tl) bv[tl] = b1[tl * 128 + u];

        float c0 = 0.f, c1 = 0.f, h0, h1v;
        hbuf[0][b0][u]     = (_Float16)0.f;
        hbuf[0][b0 + 1][u] = (_Float16)0.f;

        const _Float16* h1pG = h1p + (size_t)(8 * g + ab) * H + q * 8;  // +t*8192
        float* houtBase = out + (size_t)(8 * g) * SEQ * H;

        // initial acquire: 16-step producer lead
        if (tid == 0) {
            while (__hip_atomic_load(&flags[g], __ATOMIC_ACQUIRE,
                                     __HIP_MEMORY_SCOPE_AGENT) < 16)
                __builtin_amdgcn_s_sleep(2);
        }
        __syncthreads();

        half8 AfA[4], AfB[4];
#pragma unroll
        for (int kf = 0; kf < 4; ++kf)
            AfA[kf] = *(const half8*)(h1pG + kf * 32);     // t=0

#define C_STEP(S, PB, AfC, AfN)                                                   \
    {                                                                             \
        int sn = ((S) + 1 < TC) ? (S) + 1 : (S);                                  \
        const _Float16* hp = h1pG + (size_t)sn * (BATCH * H);                     \
        _Pragma("unroll")                                                         \
        for (int kf = 0; kf < 4; ++kf)                                            \
            AfN[kf] = *(const half8*)(hp + kf * 32);                              \
        half8 Ah[4];                                                              \
        _Pragma("unroll")                                                         \
        for (int kf = 0; kf < 4; ++kf)                                            \
            Ah[kf] = *(const half8*)&hbuf[PB][ab][kf * 32 + q * 8];               \
        f32x4 acc[4];                                                             \
        _Pragma("unroll")                                                         \
        for (int tl = 0; tl < 4; ++tl) {                                          \
            acc[tl][0] = bv[tl]; acc[tl][1] = bv[tl];                             \
            acc[tl][2] = bv[tl]; acc[tl][3] = bv[tl];                             \
        }                                                                         \
        _Pragma("unroll")                                                         \
        for (int kf = 0; kf < 4; ++kf)                                            \
            _Pragma("unroll")                                                     \
            for (int tl = 0; tl < 4; ++tl)                                        \
                acc[tl] = __builtin_amdgcn_mfma_f32_16x16x32_f16(AfC[kf], Bf[tl][kf], acc[tl], 0, 0, 0); \
        _Pragma("unroll")                                                         \
        for (int kf = 0; kf < 4; ++kf)                                            \
            _Pragma("unroll")                                                     \
            for (int tl = 0; tl < 4; ++tl)                                        \
                acc[tl] = __builtin_amdgcn_mfma_f32_16x16x32_f16(Ah[kf], Bf[tl][kf + 4], acc[tl], 0, 0, 0); \
        {                                                                         \
            float ig = sigmoid_f(acc[0][0]);                                      \
            float fg = sigmoid_f(acc[1][0]);                                      \
            float gg = tanh_f(acc[2][0]);                                         \
            float og = sigmoid_f(acc[3][0]);                                      \
            c0 = fmaf(fg, c0, ig * gg);                                           \
            h0 = og * tanh_f(c0);                                                 \
            float ig1 = sigmoid_f(acc[0][1]);                                     \
            float fg1 = sigmoid_f(acc[1][1]);                                     \
            float gg1 = tanh_f(acc[2][1]);                                        \
            float og1 = sigmoid_f(acc[3][1]);                                     \
            c1 = fmaf(fg1, c1, ig1 * gg1);                                        \
            h1v = og1 * tanh_f(c1);                                               \
        }                                                                         \
        hbuf[PB ^ 1][b0][u]     = (_Float16)h0;                                   \
        hbuf[PB ^ 1][b0 + 1][u] = (_Float16)h1v;                                  \
        houtb[(S) & 7][b0][u]     = h0;                                           \
        houtb[(S) & 7][b0 + 1][u] = h1v;                                          \
        __syncthreads();                                                          \
    }

        for (int s2 = 0; s2 < TC; s2 += 2) {
            if (s2 && (s2 & 7) == 0) {
                if (tid == 0) {
                    int tgt = (s2 + 16 > TC) ? TC : s2 + 16;
                    while (__hip_atomic_load(&flags[g], __ATOMIC_ACQUIRE,
                                             __HIP_MEMORY_SCOPE_AGENT) < tgt)
                        __builtin_amdgcn_s_sleep(2);
                }
                __syncthreads();
            }
            C_STEP(s2, 0, AfA, AfB)
            C_STEP(s2 + 1, 1, AfB, AfA)
            if ((s2 & 7) == 6) {
                int sbase = s2 - 6;
#pragma unroll
                for (int k = 0; k < 4; ++k) {
                    int idx = k * 512 + tid;
                    int u4 = idx & 31;
                    int si = (idx >> 5) & 7;
                    int bi = idx >> 8;
                    float4 v = *(const float4*)&houtb[si][bi][u4 * 4];
                    float* dst = houtBase + (size_t)bi * SEQ * H
                               + (size_t)(sbase + si) * H + u4 * 4;
                    *(float4*)dst = v;
                }
                __syncthreads();
            }
        }
#undef C_STEP
    }
}

// ---------------- launch ----------------
extern "C" void kernel_launch(void* const* d_in, const int* in_sizes, int n_in,
                              void* d_out, int out_size, void* d_ws, size_t ws_size,
                              hipStream_t stream) {
    const float* x    = (const float*)d_in[0];
    const float* Wih0 = (const float*)d_in[1];
    const float* Whh0 = (const float*)d_in[2];
    const float* bih0 = (const float*)d_in[3];
    const float* bhh0 = (const float*)d_in[4];
    const float* Wih1 = (const float*)d_in[5];
    const float* Whh1 = (const float*)d_in[6];
    const float* bih1 = (const float*)d_in[7];
    const float* bhh1 = (const float*)d_in[8];
    float* out = (float*)d_out;

    char* ws = (char*)d_ws;
    size_t off = 0;
    auto carve = [&](size_t bytes) -> char* {
        char* p = ws + off;
        off += (bytes + 255) & ~(size_t)255;
        return p;
    };

    float*     Wt0   = (float*)carve(256 * 512 * 4);
    float*     b0v   = (float*)carve(512 * 4);
    float*     b1v   = (float*)carve(512 * 4);
    _Float16*  h1p   = (_Float16*)carve((size_t)SEQ * BATCH * H * 2);
    int*       flags = (int*)carve(8 * 4);
    float*     gbuf  = (float*)carve((size_t)BATCH * SEQ * FOURH * 4);

    prep_kernel<<<517, 256, 0, stream>>>(Wih0, bih0, bhh0, bih1, bhh1, Wt0, b0v, b1v, flags);

    // layer-0 input GEMM over the full sequence: [64*2048,256] @ [256,512]
    dim3 ggrid(FOURH / BN, (BATCH * SEQ) / BM);
    gemm_bias_kernel<<<ggrid, 256, 0, stream>>>(x, 256, SEQ, 0, Wt0, b0v, gbuf, 256, 11);

    // fused pipelined 2-layer scan
    lstm_fused_kernel<<<16, 512, 0, stream>>>(gbuf, Whh0, Wih1, Whh1, b1v,
                                              h1p, out, flags);
}